// Round 10
// baseline (242.159 us; speedup 1.0000x reference)
//
#include <hip/hip_runtime.h>
#include <hip/hip_bf16.h>

// ContrastiveLoss: z (8192x1024 fp32) -> scalar
//   zn = z / max(||z||,eps); S = zn@zn^T; diag=MASK; /T; nll = -S[i,i^4096] + lse(S[i,:]); mean
// R10: 256x128 tiles (256 thr, 4 waves of 64x128, acc=128 VGPR) with
// __launch_bounds__(256,2) -> 256-VGPR cap, NO spills (R8/R9 lesson), 48KB
// static LDS -> 2 blocks/CU co-resident to hide stage/barrier/read convoys.
// Strictly-lower-triangle counting over a 32x64 grid of 256x128 tiles (1056):
// e counted only for gcol<grow; row-sums direct, col-sums via symmetry.
// Straddling tiles (cb=2rb,2rb+1) read B from inside the A slab. fp8 e4m3
// 16x16x32 MFMA, K-permuted b128 frag reads (chunks kg,kg+4), 128B rows +
// chunk^(row&7) swizzle (verified 0-conflict). Fused finale via counter (R5).

#define N 8192
#define D 1024
#define INV_T 14.285714285714286f
#define NTILES 1056
#define ACC_SCALE (INV_T / 1024.0f)  // undo fp8 x32 scaling on both operands

typedef float f32x4 __attribute__((ext_vector_type(4)));
typedef long lx2 __attribute__((ext_vector_type(2)));

__device__ inline void gload16(const void* g, void* l) {
  __builtin_amdgcn_global_load_lds(
      (const __attribute__((address_space(1))) void*)g,
      (__attribute__((address_space(3))) void*)l, 16, 0, 0);
}

// Phase 1: one wave per row, no barriers. Row-normalize, scale x32, fp8 e4m3.
__global__ __launch_bounds__(256) void k_normalize(const float* __restrict__ z,
                                                   unsigned char* __restrict__ zn8,
                                                   float* __restrict__ rowsum,
                                                   int* __restrict__ counter) {
  const int t = threadIdx.x;
  const int l = t & 63, w = t >> 6;
  const int row = blockIdx.x * 4 + w;
  if (blockIdx.x < 32) rowsum[blockIdx.x * 256 + t] = 0.0f;
  if (blockIdx.x == 32 && t == 0) *counter = 0;
  const float4* zr = (const float4*)(z + (size_t)row * D);
  float4 v[4];
  float ss = 0.f;
#pragma unroll
  for (int j = 0; j < 4; ++j) {
    v[j] = zr[l + 64 * j];
    ss += v[j].x * v[j].x + v[j].y * v[j].y + v[j].z * v[j].z + v[j].w * v[j].w;
  }
#pragma unroll
  for (int off = 32; off > 0; off >>= 1) ss += __shfl_xor(ss, off, 64);
  const float sc = 32.0f / fmaxf(sqrtf(ss), 1e-8f);  // x32 undone by ACC_SCALE
  int* op = (int*)(zn8 + (size_t)row * D);
#pragma unroll
  for (int j = 0; j < 4; ++j) {
    int p = __builtin_amdgcn_cvt_pk_fp8_f32(v[j].x * sc, v[j].y * sc, 0, false);
    p = __builtin_amdgcn_cvt_pk_fp8_f32(v[j].z * sc, v[j].w * sc, p, true);
    op[l + 64 * j] = p;
  }
}

// Phase 2: 256x128 tile per block over the strictly-lower triangle.
// Tile (rb, cb): rows [rb*256, +256), cols [cb*128, +128), cb <= 2rb+1.
// 4 waves, wave w covers rows [w*64, +64) x all 128 cols: acc 4x8 f32x4.
__global__ __launch_bounds__(256, 2) void k_tile(const unsigned char* __restrict__ zn8,
                                                 float* __restrict__ rowsum,
                                                 float* __restrict__ pos,
                                                 int* __restrict__ counter,
                                                 float* __restrict__ out) {
  __shared__ __align__(16) char smem[49152];  // A 32KB + B 16KB
  const int tid = threadIdx.x;
  const int w = tid >> 6, l = tid & 63;

  // decode blockIdx -> (rb, cb): b = rb(rb+1) + cb, cb in [0, 2rb+2)
  const int b = blockIdx.x;
  int rb = (int)((sqrtf(4.0f * (float)b + 1.0f) - 1.0f) * 0.5f);
  if (rb * (rb + 1) > b) --rb;
  if ((rb + 1) * (rb + 2) <= b) ++rb;
  const int cb = b - rb * (rb + 1);
  const bool straddle = (cb >> 1) == rb;  // B band inside A band

  const int m = l & 15, kg = l >> 4;
  const int rowA0 = rb * 256, colB0 = cb * 128;

  f32x4 acc[4][8] = {};

  // staging slot maps (16B chunks, 128B rows, chunk c stored at c^(row&7))
  int srowA[8], scolA[8];
#pragma unroll
  for (int j = 0; j < 8; ++j) {
    int s = j * 256 + tid;
    srowA[j] = s >> 3;
    scolA[j] = (s & 7) ^ ((s >> 3) & 7);
  }
  // B uses j=0..3 of the same pattern (128 rows)

  // fragment reads: logical chunks kg and kg+4 (K-permuted; A/B identical)
  const int csw0 = (kg ^ (m & 7)) * 16;
  const int csw1 = ((kg + 4) ^ (m & 7)) * 16;

  char* const ab = smem;
  char* const bb = straddle ? (smem + (cb - 2 * rb) * 16384) : (smem + 32768);

  for (int kt = 0; kt < 8; ++kt) {
    const size_t kb = (size_t)kt * 128;
    {  // stage slab kt (async -> LDS); barrier below drains vmcnt
#pragma unroll
      for (int j = 0; j < 8; ++j) {
        const int s = j * 256 + tid;
        gload16((const char*)zn8 + ((size_t)(rowA0 + srowA[j]) * D + kb + scolA[j] * 16), ab + s * 16);
      }
      if (!straddle) {
#pragma unroll
        for (int j = 0; j < 4; ++j) {
          const int s = j * 256 + tid;
          gload16((const char*)zn8 + ((size_t)(colB0 + srowA[j]) * D + kb + scolA[j] * 16),
                  smem + 32768 + s * 16);
        }
      }
    }
    __syncthreads();  // staging complete

    lx2 a0[4], a1[4];
#pragma unroll
    for (int mt = 0; mt < 4; ++mt) {
      const char* rp = ab + (w * 64 + mt * 16 + m) * 128;
      a0[mt] = *(const lx2*)(rp + csw0);
      a1[mt] = *(const lx2*)(rp + csw1);
    }
#pragma unroll
    for (int nt = 0; nt < 8; ++nt) {
      const char* rp = bb + (nt * 16 + m) * 128;
      const lx2 b0 = *(const lx2*)(rp + csw0);
      const lx2 b1 = *(const lx2*)(rp + csw1);
#pragma unroll
      for (int mt = 0; mt < 4; ++mt) {
        acc[mt][nt] = __builtin_amdgcn_mfma_f32_16x16x32_fp8_fp8(a0[mt].x, b0.x, acc[mt][nt], 0, 0, 0);
        acc[mt][nt] = __builtin_amdgcn_mfma_f32_16x16x32_fp8_fp8(a0[mt].y, b0.y, acc[mt][nt], 0, 0, 0);
        acc[mt][nt] = __builtin_amdgcn_mfma_f32_16x16x32_fp8_fp8(a1[mt].x, b1.x, acc[mt][nt], 0, 0, 0);
        acc[mt][nt] = __builtin_amdgcn_mfma_f32_16x16x32_fp8_fp8(a1[mt].y, b1.y, acc[mt][nt], 0, 0, 0);
      }
    }
    __syncthreads();  // all frags consumed before next slab overwrites
  }

  // Epilogue. C/D layout: col=l&15, row=(l>>4)*4+reg. Count only gcol<grow;
  // row-sums direct, col-sums via symmetry (exactly the transpose set).
  const int quad = l >> 4;
  const int col = l & 15;
  float cs[8] = {0.f, 0.f, 0.f, 0.f, 0.f, 0.f, 0.f, 0.f};
#pragma unroll
  for (int mt = 0; mt < 4; ++mt) {
    float rs[4] = {0.f, 0.f, 0.f, 0.f};
#pragma unroll
    for (int nt = 0; nt < 8; ++nt) {
      const int gcol = colB0 + nt * 16 + col;
#pragma unroll
      for (int r = 0; r < 4; ++r) {
        const int grow = rowA0 + w * 64 + mt * 16 + quad * 4 + r;
        const float t = acc[mt][nt][r] * ACC_SCALE;
        if (gcol == (grow ^ (N / 2)) && gcol < grow) {  // pos pair (lower copy)
          __hip_atomic_store(&pos[grow], t, __ATOMIC_RELAXED, __HIP_MEMORY_SCOPE_AGENT);
          __hip_atomic_store(&pos[gcol], t, __ATOMIC_RELAXED, __HIP_MEMORY_SCOPE_AGENT);
        }
        const float e = (gcol < grow) ? __expf(t - INV_T) : 0.0f;
        rs[r] += e;
        cs[nt] += e;
      }
    }
#pragma unroll
    for (int off = 1; off < 16; off <<= 1) {
#pragma unroll
      for (int r = 0; r < 4; ++r) rs[r] += __shfl_xor(rs[r], off, 64);
    }
    if (col == 0) {
#pragma unroll
      for (int r = 0; r < 4; ++r)
        atomicAdd(&rowsum[rowA0 + w * 64 + mt * 16 + quad * 4 + r], rs[r]);
    }
  }
#pragma unroll
  for (int nt = 0; nt < 8; ++nt) {  // col sums -> row-sums for cols (symmetry)
    cs[nt] += __shfl_xor(cs[nt], 16, 64);
    cs[nt] += __shfl_xor(cs[nt], 32, 64);
  }
  if (l < 16) {
#pragma unroll
    for (int nt = 0; nt < 8; ++nt)
      atomicAdd(&rowsum[colB0 + nt * 16 + l], cs[nt]);
  }

  // Fused finale (R5-proven): last block computes out = mean(-pos + C + log(rowsum)).
  __shared__ int s_last;
  __syncthreads();
  __threadfence();  // device-scope release of this block's atomics/stores
  if (tid == 0) {
    int old = __hip_atomic_fetch_add(counter, 1, __ATOMIC_ACQ_REL, __HIP_MEMORY_SCOPE_AGENT);
    s_last = (old == NTILES - 1);
  }
  __syncthreads();
  if (s_last) {
    float s = 0.f;
    for (int i = tid; i < N; i += 256) {
      const float rsv = __hip_atomic_load(&rowsum[i], __ATOMIC_RELAXED, __HIP_MEMORY_SCOPE_AGENT);
      const float pv = __hip_atomic_load(&pos[i], __ATOMIC_RELAXED, __HIP_MEMORY_SCOPE_AGENT);
      s += INV_T + __logf(rsv) - pv;
    }
#pragma unroll
    for (int off = 32; off > 0; off >>= 1) s += __shfl_down(s, off, 64);
    float* red = (float*)smem;
    if (l == 0) red[w] = s;
    __syncthreads();
    if (tid == 0) out[0] = (red[0] + red[1] + red[2] + red[3]) * (1.0f / N);
  }
}

extern "C" void kernel_launch(void* const* d_in, const int* in_sizes, int n_in,
                              void* d_out, int out_size, void* d_ws, size_t ws_size,
                              hipStream_t stream) {
  const float* z = (const float*)d_in[0];
  float* out = (float*)d_out;
  char* ws = (char*)d_ws;
  unsigned char* zn8 = (unsigned char*)ws;                    // 8 MiB fp8
  float* rowsum = (float*)(ws + (size_t)N * D);               // 32 KiB
  float* pos = (float*)(ws + (size_t)N * D + (size_t)N * 4);  // 32 KiB
  int* counter = (int*)(ws + (size_t)N * D + (size_t)N * 8);  // 4 B

  k_normalize<<<N / 4, 256, 0, stream>>>(z, zn8, rowsum, counter);
  k_tile<<<NTILES, 256, 0, stream>>>(zn8, rowsum, pos, counter, out);
}

// Round 11
// 212.530 us; speedup vs baseline: 1.1394x; 1.1394x over previous
//
#include <hip/hip_runtime.h>
#include <hip/hip_bf16.h>

// ContrastiveLoss: z (8192x1024 fp32) -> scalar
//   zn = z / max(||z||,eps); S = zn@zn^T; diag=MASK; /T; nll = -S[i,i^4096] + lse(S[i,:]); mean
// R11 = R7 + R4 + R5: fp8 e4m3 16x16x32 MFMA with K-permuted b128 frag reads
// (chunks kg,kg+4; 128B rows + chunk^(row&7) swizzle — verified 0-conflict),
// DOUBLE-BUFFERED BK=128 slabs (2x64KB LDS; prefetch kt+1 issues before kt's
// ~5kcyc MFMA phase so the pre-barrier vmcnt drain is ~free — R4 ran 77% duty
// with this exact structure), 256x256 lower-triangle tiles, fused finale via
// completion counter (saves the k_final launch, R5/R10-proven).

#define N 8192
#define D 1024
#define INV_T 14.285714285714286f
#define NTILES 528
#define ACC_SCALE (INV_T / 1024.0f)  // undo fp8 x32 scaling on both operands

typedef float f32x4 __attribute__((ext_vector_type(4)));
typedef long lx2 __attribute__((ext_vector_type(2)));

__device__ inline void gload16(const void* g, void* l) {
  __builtin_amdgcn_global_load_lds(
      (const __attribute__((address_space(1))) void*)g,
      (__attribute__((address_space(3))) void*)l, 16, 0, 0);
}

// Phase 1: one wave per row, no barriers. Row-normalize, scale x32, fp8 e4m3.
__global__ __launch_bounds__(256) void k_normalize(const float* __restrict__ z,
                                                   unsigned char* __restrict__ zn8,
                                                   float* __restrict__ rowsum,
                                                   int* __restrict__ counter) {
  const int t = threadIdx.x;
  const int l = t & 63, w = t >> 6;
  const int row = blockIdx.x * 4 + w;
  if (blockIdx.x < 32) rowsum[blockIdx.x * 256 + t] = 0.0f;
  if (blockIdx.x == 32 && t == 0) *counter = 0;
  const float4* zr = (const float4*)(z + (size_t)row * D);
  float4 v[4];
  float ss = 0.f;
#pragma unroll
  for (int j = 0; j < 4; ++j) {
    v[j] = zr[l + 64 * j];
    ss += v[j].x * v[j].x + v[j].y * v[j].y + v[j].z * v[j].z + v[j].w * v[j].w;
  }
#pragma unroll
  for (int off = 32; off > 0; off >>= 1) ss += __shfl_xor(ss, off, 64);
  const float sc = 32.0f / fmaxf(sqrtf(ss), 1e-8f);  // x32 undone by ACC_SCALE
  int* op = (int*)(zn8 + (size_t)row * D);
#pragma unroll
  for (int j = 0; j < 4; ++j) {
    int p = __builtin_amdgcn_cvt_pk_fp8_f32(v[j].x * sc, v[j].y * sc, 0, false);
    p = __builtin_amdgcn_cvt_pk_fp8_f32(v[j].z * sc, v[j].w * sc, p, true);
    op[l + 64 * j] = p;
  }
}

// Phase 2: 256x256 lower-triangle tile per block, 512 threads (8 waves, 4x2).
// fp8 BK=128 slab: A 32KB + B 32KB, double-buffered = 128KB dynamic LDS.
__global__ __launch_bounds__(512, 2) void k_tile(const unsigned char* __restrict__ zn8,
                                                 float* __restrict__ rowsum,
                                                 float* __restrict__ pos,
                                                 int* __restrict__ counter,
                                                 float* __restrict__ out) {
  extern __shared__ __align__(16) char smem[];  // 131072
  const int tid = threadIdx.x;
  const int w = tid >> 6, l = tid & 63;

  // decode blockIdx -> lower-triangle (tr, tc), tr >= tc, over 32x32 tile grid
  const int b = blockIdx.x;
  int tr = (int)((sqrtf(8.0f * (float)b + 1.0f) - 1.0f) * 0.5f);
  if (tr * (tr + 1) / 2 > b) --tr;
  if ((tr + 1) * (tr + 2) / 2 <= b) ++tr;
  const int tc = b - tr * (tr + 1) / 2;
  const bool diag = (tr == tc);

  const int wr = w >> 1, wc = w & 1;
  const int m = l & 15, kg = l >> 4;
  const int rowA0 = tr * 256, colB0 = tc * 256;

  f32x4 acc[4][8] = {};

  // staging: per matrix per slab 2048 slots x 16B (256 rows x 8 chunks).
  // phys slot s -> row s>>3; phys chunk s&7 holds logical chunk (s&7)^(row&7).
  int srow[4], scol[4];
#pragma unroll
  for (int j = 0; j < 4; ++j) {
    int s = j * 512 + tid;
    int r = s >> 3;
    srow[j] = r;
    scol[j] = (s & 7) ^ (r & 7);
  }

  // fragment reads: logical chunks kg and kg+4 (K-permuted; A/B identical)
  const int csw0 = (kg ^ (m & 7)) * 16;
  const int csw1 = ((kg + 4) ^ (m & 7)) * 16;

  // prologue: stage slab kt=0 into buffer 0
  {
    char* ab = smem;
#pragma unroll
    for (int j = 0; j < 4; ++j) {
      const int s = j * 512 + tid;
      gload16((const char*)zn8 + ((size_t)(rowA0 + srow[j]) * D + scol[j] * 16), ab + s * 16);
    }
    if (!diag) {
      char* bb = smem + 32768;
#pragma unroll
      for (int j = 0; j < 4; ++j) {
        const int s = j * 512 + tid;
        gload16((const char*)zn8 + ((size_t)(colB0 + srow[j]) * D + scol[j] * 16), bb + s * 16);
      }
    }
  }
  __syncthreads();

  for (int kt = 0; kt < 8; ++kt) {
    if (kt < 7) {  // async prefetch kt+1 into other buffer; overlaps MFMA below
      const size_t kb = (size_t)(kt + 1) * 128;
      char* ab = smem + ((kt + 1) & 1) * 65536;
#pragma unroll
      for (int j = 0; j < 4; ++j) {
        const int s = j * 512 + tid;
        gload16((const char*)zn8 + ((size_t)(rowA0 + srow[j]) * D + kb + scol[j] * 16), ab + s * 16);
      }
      if (!diag) {
        char* bb = ab + 32768;
#pragma unroll
        for (int j = 0; j < 4; ++j) {
          const int s = j * 512 + tid;
          gload16((const char*)zn8 + ((size_t)(colB0 + srow[j]) * D + kb + scol[j] * 16), bb + s * 16);
        }
      }
    }
    const char* ab = smem + (kt & 1) * 65536;
    const char* bb = diag ? ab : (ab + 32768);

    lx2 a0[4], a1[4];
#pragma unroll
    for (int mt = 0; mt < 4; ++mt) {
      const char* rp = ab + (wr * 64 + mt * 16 + m) * 128;
      a0[mt] = *(const lx2*)(rp + csw0);
      a1[mt] = *(const lx2*)(rp + csw1);
    }
#pragma unroll
    for (int nt = 0; nt < 8; ++nt) {
      const char* rp = bb + (wc * 128 + nt * 16 + m) * 128;
      const lx2 b0 = *(const lx2*)(rp + csw0);
      const lx2 b1 = *(const lx2*)(rp + csw1);
#pragma unroll
      for (int mt = 0; mt < 4; ++mt) {
        acc[mt][nt] = __builtin_amdgcn_mfma_f32_16x16x32_fp8_fp8(a0[mt].x, b0.x, acc[mt][nt], 0, 0, 0);
        acc[mt][nt] = __builtin_amdgcn_mfma_f32_16x16x32_fp8_fp8(a0[mt].y, b0.y, acc[mt][nt], 0, 0, 0);
        acc[mt][nt] = __builtin_amdgcn_mfma_f32_16x16x32_fp8_fp8(a1[mt].x, b1.x, acc[mt][nt], 0, 0, 0);
        acc[mt][nt] = __builtin_amdgcn_mfma_f32_16x16x32_fp8_fp8(a1[mt].y, b1.y, acc[mt][nt], 0, 0, 0);
      }
    }
    __syncthreads();  // drains prefetch (issued ~5kcyc ago -> ~free) + buffer guard
  }

  // Epilogue. C/D layout: col=l&15, row=(l>>4)*4+reg.
  const int quad = l >> 4;
  const int col = l & 15;
  float cs[8] = {0.f, 0.f, 0.f, 0.f, 0.f, 0.f, 0.f, 0.f};
#pragma unroll
  for (int mt = 0; mt < 4; ++mt) {
    float rs[4] = {0.f, 0.f, 0.f, 0.f};
#pragma unroll
    for (int nt = 0; nt < 8; ++nt) {
      const int gcol = colB0 + wc * 128 + nt * 16 + col;
#pragma unroll
      for (int r = 0; r < 4; ++r) {
        const int grow = rowA0 + wr * 64 + mt * 16 + quad * 4 + r;
        const float t = acc[mt][nt][r] * ACC_SCALE;
        if (gcol == (grow ^ (N / 2))) {  // pos pair; never in diag tiles
          __hip_atomic_store(&pos[grow], t, __ATOMIC_RELAXED, __HIP_MEMORY_SCOPE_AGENT);
          __hip_atomic_store(&pos[gcol], t, __ATOMIC_RELAXED, __HIP_MEMORY_SCOPE_AGENT);
        }
        const float e = (gcol == grow) ? 0.0f : __expf(t - INV_T);
        rs[r] += e;
        cs[nt] += e;
      }
    }
#pragma unroll
    for (int off = 1; off < 16; off <<= 1) {
#pragma unroll
      for (int r = 0; r < 4; ++r) rs[r] += __shfl_xor(rs[r], off, 64);
    }
    if (col == 0) {
#pragma unroll
      for (int r = 0; r < 4; ++r)
        atomicAdd(&rowsum[rowA0 + wr * 64 + mt * 16 + quad * 4 + r], rs[r]);
    }
  }
  if (!diag) {  // col sums = row-sums for block tc rows (symmetry)
#pragma unroll
    for (int nt = 0; nt < 8; ++nt) {
      cs[nt] += __shfl_xor(cs[nt], 16, 64);
      cs[nt] += __shfl_xor(cs[nt], 32, 64);
    }
    if (l < 16) {
#pragma unroll
      for (int nt = 0; nt < 8; ++nt)
        atomicAdd(&rowsum[colB0 + wc * 128 + nt * 16 + l], cs[nt]);
    }
  }

  // Fused finale (R5-proven): last block computes out = mean(-pos + C + log(rowsum)).
  __shared__ int s_last;
  __syncthreads();
  __threadfence();  // device-scope release of this block's atomics/stores
  if (tid == 0) {
    int old = __hip_atomic_fetch_add(counter, 1, __ATOMIC_ACQ_REL, __HIP_MEMORY_SCOPE_AGENT);
    s_last = (old == NTILES - 1);
  }
  __syncthreads();
  if (s_last) {
    float s = 0.f;
    for (int i = tid; i < N; i += 512) {
      const float rsv = __hip_atomic_load(&rowsum[i], __ATOMIC_RELAXED, __HIP_MEMORY_SCOPE_AGENT);
      const float pv = __hip_atomic_load(&pos[i], __ATOMIC_RELAXED, __HIP_MEMORY_SCOPE_AGENT);
      s += INV_T + __logf(rsv) - pv;
    }
#pragma unroll
    for (int off = 32; off > 0; off >>= 1) s += __shfl_down(s, off, 64);
    float* red = (float*)smem;
    if (l == 0) red[w] = s;
    __syncthreads();
    if (tid == 0) {
      float tot = 0.f;
#pragma unroll
      for (int j = 0; j < 8; ++j) tot += red[j];
      out[0] = tot * (1.0f / N);
    }
  }
}

extern "C" void kernel_launch(void* const* d_in, const int* in_sizes, int n_in,
                              void* d_out, int out_size, void* d_ws, size_t ws_size,
                              hipStream_t stream) {
  const float* z = (const float*)d_in[0];
  float* out = (float*)d_out;
  char* ws = (char*)d_ws;
  unsigned char* zn8 = (unsigned char*)ws;                    // 8 MiB fp8
  float* rowsum = (float*)(ws + (size_t)N * D);               // 32 KiB
  float* pos = (float*)(ws + (size_t)N * D + (size_t)N * 4);  // 32 KiB
  int* counter = (int*)(ws + (size_t)N * D + (size_t)N * 8);  // 4 B

  static bool attr_set = false;
  if (!attr_set) {  // host-side attribute, idempotent, not a stream op
    hipFuncSetAttribute((const void*)k_tile,
                        hipFuncAttributeMaxDynamicSharedMemorySize, 131072);
    attr_set = true;
  }

  k_normalize<<<N / 4, 256, 0, stream>>>(z, zn8, rowsum, counter);
  k_tile<<<NTILES, 512, 131072, stream>>>(zn8, rowsum, pos, counter, out);
}

// Round 12
// 155.268 us; speedup vs baseline: 1.5596x; 1.3688x over previous
//
#include <hip/hip_runtime.h>
#include <hip/hip_bf16.h>

// ContrastiveLoss: z (8192x1024 fp32) -> scalar
//   zn = z / max(||z||,eps); S = zn@zn^T; diag=MASK; /T; nll = -S[i,i^4096] + lse(S[i,:]); mean
// R12: R7's proven fp8 K-loop, but SINGLE-buffered 64KB static LDS so TWO
// blocks co-reside per CU (VGPR 104 <= 128, 16 waves) — block-level pipelining
// replaces double-buffering: one block's stage/drain convoy overlaps the
// other's MFMA phase (m114). NO per-block __threadfence/fused finale (R5/R11:
// that costs ~75 µs in L2 writebacks). fp8 e4m3 16x16x32 MFMA, K-permuted
// b128 frag reads (chunks kg,kg+4), 128B rows + chunk^(row&7) swizzle
// (verified 0-conflict). Lower-triangle 256x256 tiles; fixed-shift logsumexp
// partials via atomicAdd; wave-per-row normalize; separate k_final.

#define N 8192
#define D 1024
#define INV_T 14.285714285714286f
#define NTILES 528
#define ACC_SCALE (INV_T / 1024.0f)  // undo fp8 x32 scaling on both operands

typedef float f32x4 __attribute__((ext_vector_type(4)));
typedef long lx2 __attribute__((ext_vector_type(2)));

__device__ inline void gload16(const void* g, void* l) {
  __builtin_amdgcn_global_load_lds(
      (const __attribute__((address_space(1))) void*)g,
      (__attribute__((address_space(3))) void*)l, 16, 0, 0);
}

// Phase 1: one wave per row, no barriers. Row-normalize, scale x32, fp8 e4m3.
__global__ __launch_bounds__(256) void k_normalize(const float* __restrict__ z,
                                                   unsigned char* __restrict__ zn8,
                                                   float* __restrict__ rowsum) {
  const int t = threadIdx.x;
  const int l = t & 63, w = t >> 6;
  const int row = blockIdx.x * 4 + w;
  if (blockIdx.x < 32) rowsum[blockIdx.x * 256 + t] = 0.0f;
  const float4* zr = (const float4*)(z + (size_t)row * D);
  float4 v[4];
  float ss = 0.f;
#pragma unroll
  for (int j = 0; j < 4; ++j) {
    v[j] = zr[l + 64 * j];
    ss += v[j].x * v[j].x + v[j].y * v[j].y + v[j].z * v[j].z + v[j].w * v[j].w;
  }
#pragma unroll
  for (int off = 32; off > 0; off >>= 1) ss += __shfl_xor(ss, off, 64);
  const float sc = 32.0f / fmaxf(sqrtf(ss), 1e-8f);  // x32 undone by ACC_SCALE
  int* op = (int*)(zn8 + (size_t)row * D);
#pragma unroll
  for (int j = 0; j < 4; ++j) {
    int p = __builtin_amdgcn_cvt_pk_fp8_f32(v[j].x * sc, v[j].y * sc, 0, false);
    p = __builtin_amdgcn_cvt_pk_fp8_f32(v[j].z * sc, v[j].w * sc, p, true);
    op[l + 64 * j] = p;
  }
}

// Phase 2: 256x256 lower-triangle tile per block, 512 threads (8 waves, 4x2).
// fp8 BK=128 slab: A 32KB + B 32KB single-buffered = 64KB static -> 2 blocks/CU.
__global__ __launch_bounds__(512, 2) void k_tile(const unsigned char* __restrict__ zn8,
                                                 float* __restrict__ rowsum,
                                                 float* __restrict__ pos) {
  __shared__ __align__(16) char smem[65536];
  const int tid = threadIdx.x;
  const int w = tid >> 6, l = tid & 63;

  // decode blockIdx -> lower-triangle (tr, tc), tr >= tc, over 32x32 tile grid
  const int b = blockIdx.x;
  int tr = (int)((sqrtf(8.0f * (float)b + 1.0f) - 1.0f) * 0.5f);
  if (tr * (tr + 1) / 2 > b) --tr;
  if ((tr + 1) * (tr + 2) / 2 <= b) ++tr;
  const int tc = b - tr * (tr + 1) / 2;
  const bool diag = (tr == tc);

  const int wr = w >> 1, wc = w & 1;
  const int m = l & 15, kg = l >> 4;
  const int rowA0 = tr * 256, colB0 = tc * 256;

  f32x4 acc[4][8] = {};

  // staging: per matrix per slab 2048 slots x 16B (256 rows x 8 chunks).
  // phys slot s -> row s>>3; phys chunk s&7 holds logical chunk (s&7)^(row&7).
  int srow[4], scol[4];
#pragma unroll
  for (int j = 0; j < 4; ++j) {
    int s = j * 512 + tid;
    int r = s >> 3;
    srow[j] = r;
    scol[j] = (s & 7) ^ (r & 7);
  }

  // fragment reads: logical chunks kg and kg+4 (K-permuted; A/B identical)
  const int csw0 = (kg ^ (m & 7)) * 16;
  const int csw1 = ((kg + 4) ^ (m & 7)) * 16;

  for (int kt = 0; kt < 8; ++kt) {
    const size_t kb = (size_t)kt * 128;
    {  // stage slab kt (async -> LDS); barrier below drains vmcnt
      char* ab = smem;
#pragma unroll
      for (int j = 0; j < 4; ++j) {
        const int s = j * 512 + tid;
        gload16((const char*)zn8 + ((size_t)(rowA0 + srow[j]) * D + kb + scol[j] * 16), ab + s * 16);
      }
      if (!diag) {
        char* bb = smem + 32768;
#pragma unroll
        for (int j = 0; j < 4; ++j) {
          const int s = j * 512 + tid;
          gload16((const char*)zn8 + ((size_t)(colB0 + srow[j]) * D + kb + scol[j] * 16), bb + s * 16);
        }
      }
    }
    __syncthreads();  // staging complete

    const char* ab = smem;
    const char* bb = diag ? ab : (ab + 32768);
    lx2 a0[4], a1[4];
#pragma unroll
    for (int mt = 0; mt < 4; ++mt) {
      const char* rp = ab + (wr * 64 + mt * 16 + m) * 128;
      a0[mt] = *(const lx2*)(rp + csw0);
      a1[mt] = *(const lx2*)(rp + csw1);
    }
#pragma unroll
    for (int nt = 0; nt < 8; ++nt) {
      const char* rp = bb + (wc * 128 + nt * 16 + m) * 128;
      const lx2 b0 = *(const lx2*)(rp + csw0);
      const lx2 b1 = *(const lx2*)(rp + csw1);
#pragma unroll
      for (int mt = 0; mt < 4; ++mt) {
        acc[mt][nt] = __builtin_amdgcn_mfma_f32_16x16x32_fp8_fp8(a0[mt].x, b0.x, acc[mt][nt], 0, 0, 0);
        acc[mt][nt] = __builtin_amdgcn_mfma_f32_16x16x32_fp8_fp8(a0[mt].y, b0.y, acc[mt][nt], 0, 0, 0);
        acc[mt][nt] = __builtin_amdgcn_mfma_f32_16x16x32_fp8_fp8(a1[mt].x, b1.x, acc[mt][nt], 0, 0, 0);
        acc[mt][nt] = __builtin_amdgcn_mfma_f32_16x16x32_fp8_fp8(a1[mt].y, b1.y, acc[mt][nt], 0, 0, 0);
      }
    }
    __syncthreads();  // all frags consumed before next slab overwrites
  }

  // Epilogue. C/D layout: col=l&15, row=(l>>4)*4+reg.
  const int quad = l >> 4;
  const int col = l & 15;
  float cs[8] = {0.f, 0.f, 0.f, 0.f, 0.f, 0.f, 0.f, 0.f};
#pragma unroll
  for (int mt = 0; mt < 4; ++mt) {
    float rs[4] = {0.f, 0.f, 0.f, 0.f};
#pragma unroll
    for (int nt = 0; nt < 8; ++nt) {
      const int gcol = colB0 + wc * 128 + nt * 16 + col;
#pragma unroll
      for (int r = 0; r < 4; ++r) {
        const int grow = rowA0 + wr * 64 + mt * 16 + quad * 4 + r;
        const float t = acc[mt][nt][r] * ACC_SCALE;
        if (gcol == (grow ^ (N / 2))) {  // pos pair; never in diag tiles
          pos[grow] = t;
          pos[gcol] = t;  // S symmetric
        }
        const float e = (gcol == grow) ? 0.0f : __expf(t - INV_T);
        rs[r] += e;
        cs[nt] += e;
      }
    }
#pragma unroll
    for (int off = 1; off < 16; off <<= 1) {
#pragma unroll
      for (int r = 0; r < 4; ++r) rs[r] += __shfl_xor(rs[r], off, 64);
    }
    if (col == 0) {
#pragma unroll
      for (int r = 0; r < 4; ++r)
        atomicAdd(&rowsum[rowA0 + wr * 64 + mt * 16 + quad * 4 + r], rs[r]);
    }
  }
  if (!diag) {  // col sums = row-sums for block tc rows (symmetry)
#pragma unroll
    for (int nt = 0; nt < 8; ++nt) {
      cs[nt] += __shfl_xor(cs[nt], 16, 64);
      cs[nt] += __shfl_xor(cs[nt], 32, 64);
    }
    if (l < 16) {
#pragma unroll
      for (int nt = 0; nt < 8; ++nt)
        atomicAdd(&rowsum[colB0 + wc * 128 + nt * 16 + l], cs[nt]);
    }
  }
}

// Phase 3: single block: out = mean(-pos + C + log(rowsum)).
__global__ __launch_bounds__(1024) void k_final(const float* __restrict__ rowsum,
                                                const float* __restrict__ pos,
                                                float* __restrict__ out) {
  const int t = threadIdx.x;
  float s = 0.f;
  for (int i = t; i < N; i += 1024) s += INV_T + __logf(rowsum[i]) - pos[i];
#pragma unroll
  for (int off = 32; off > 0; off >>= 1) s += __shfl_down(s, off, 64);
  __shared__ float red[16];
  if ((t & 63) == 0) red[t >> 6] = s;
  __syncthreads();
  if (t == 0) {
    float tot = 0.f;
#pragma unroll
    for (int j = 0; j < 16; ++j) tot += red[j];
    out[0] = tot * (1.0f / N);
  }
}

extern "C" void kernel_launch(void* const* d_in, const int* in_sizes, int n_in,
                              void* d_out, int out_size, void* d_ws, size_t ws_size,
                              hipStream_t stream) {
  const float* z = (const float*)d_in[0];
  float* out = (float*)d_out;
  char* ws = (char*)d_ws;
  unsigned char* zn8 = (unsigned char*)ws;                    // 8 MiB fp8
  float* rowsum = (float*)(ws + (size_t)N * D);               // 32 KiB
  float* pos = (float*)(ws + (size_t)N * D + (size_t)N * 4);  // 32 KiB

  k_normalize<<<N / 4, 256, 0, stream>>>(z, zn8, rowsum);
  k_tile<<<NTILES, 512, 0, stream>>>(zn8, rowsum, pos);
  k_final<<<1, 1024, 0, stream>>>(rowsum, pos, out);
}